// Round 14
// baseline (359.051 us; speedup 1.0000x reference)
//
#include <hip/hip_runtime.h>

#define CH 128
#define CHUNK 4096

typedef float v2f __attribute__((ext_vector_type(2)));
typedef __attribute__((ext_vector_type(8))) short bf16x8;   // 8 bf16 (4 VGPRs)
typedef __attribute__((ext_vector_type(4))) float f32x4;    // MFMA acc

// ---------------------------------------------------------------- fp8 helpers (OCP e4m3)

__device__ __forceinline__ void fp8acc4(unsigned w, float* a) {
  v2f p0 = __builtin_amdgcn_cvt_pk_f32_fp8(w, false);
  v2f p1 = __builtin_amdgcn_cvt_pk_f32_fp8(w, true);
  a[0] += p0.x; a[1] += p0.y; a[2] += p1.x; a[3] += p1.y;
}
__device__ __forceinline__ void fp8acc8(uint2 v, float* a) {
  fp8acc4(v.x, a); fp8acc4(v.y, a + 4);
}
__device__ __forceinline__ unsigned fp8pk4(float a, float b, float c, float d) {
  int w = 0;
  w = __builtin_amdgcn_cvt_pk_fp8_f32(a, b, w, false);
  w = __builtin_amdgcn_cvt_pk_fp8_f32(c, d, w, true);
  return (unsigned)w;
}

// ---------------------------------------------------------------- bf16 helpers

__device__ __forceinline__ unsigned bfpack2(float a, float b) {
  unsigned ua = __float_as_uint(a); ua += 0x7FFF + ((ua >> 16) & 1);
  unsigned ub = __float_as_uint(b); ub += 0x7FFF + ((ub >> 16) & 1);
  return (ua >> 16) | (ub & 0xFFFF0000u);
}
__device__ __forceinline__ ushort bf16of(float a) {
  unsigned ua = __float_as_uint(a); ua += 0x7FFF + ((ua >> 16) & 1);
  return (ushort)(ua >> 16);
}
__device__ __forceinline__ uint2 fp8tobf4(unsigned w) {  // 4 fp8 -> 4 bf16
  v2f p0 = __builtin_amdgcn_cvt_pk_f32_fp8(w, false);
  v2f p1 = __builtin_amdgcn_cvt_pk_f32_fp8(w, true);
  return make_uint2(bfpack2(p0.x, p0.y), bfpack2(p1.x, p1.y));
}

// ---------------------------------------------------------------- utilities

__device__ __forceinline__ int edge_at(const void* ei, long long i, int is64) {
  if (is64) return (int)((const long long*)ei)[i];
  return ((const int*)ei)[i];
}

// merged setup: dtype detect + counter zero + bf16 weight prep (1 block)
__global__ void k_setup(const int* ei, int* flag, int* bcnt, int* rcnt,
                        const float* __restrict__ W1, const float* __restrict__ b1,
                        const float* __restrict__ W2, const float* __restrict__ b2,
                        ushort* __restrict__ Wt1, ushort* __restrict__ Wt2,
                        float* __restrict__ b1p, float* __restrict__ b2p) {
  int t = threadIdx.x;
  if (t == 0) {
    int is64 = 1;
    for (int k = 1; k < 128; k += 2)
      if (ei[k] != 0) { is64 = 0; break; }
    *flag = is64;
  }
  for (int i = t; i < 256 * 16; i += 256) { bcnt[i] = 0; rcnt[i] = 0; }
  for (int i = t; i < 128 * 128; i += 256) {
    int n = i >> 7, k = i & 127;
    Wt1[i] = bf16of(W1[(size_t)k * CH + n]);
    int ko = (k & 7) * 16 + (k >> 3);
    Wt2[i] = bf16of(W2[(size_t)ko * CH + n]);
  }
  if (t < CH) {
    int o = (t & 7) * 16 + (t >> 3);
    b1p[t] = b1[o];
    b2p[t] = b2[o];
  }
}

// P1: per-bucket edge counts for BOTH c-buckets and r-buckets
__global__ __launch_bounds__(256) void kb_count(const void* ei, const int* flag,
                                                int* bcnt, int* rcnt, int E, int N) {
  __shared__ int hist[256], rhist[256];
  int t = threadIdx.x;
  hist[t] = 0; rhist[t] = 0;
  __syncthreads();
  int f = *flag;
  for (int e = blockIdx.x * 256 + t; e < E; e += gridDim.x * 256) {
    int r = edge_at(ei, e, f);
    int c = edge_at(ei, (long long)E + e, f);
    if ((unsigned)r < (unsigned)N && (unsigned)c < (unsigned)N) {
      atomicAdd(&hist[c >> 8], 1);
      atomicAdd(&rhist[r >> 8], 1);
    }
  }
  __syncthreads();
  if (hist[t] > 0) atomicAdd(&bcnt[t * 16], hist[t]);
  if (rhist[t] > 0) atomicAdd(&rcnt[t * 16], rhist[t]);
}

// P2: scan both bucket-count arrays -> bases + cursors; rowptr[N]=total
__global__ void kb_scan(const int* bcnt, int* bbase, int* gcursor,
                        const int* rcnt, int* rbase, int* rcursor,
                        int* rowptr, int NB, int N) {
  __shared__ int tmp[256];
  int t = threadIdx.x;
  int v = (t < NB) ? bcnt[t * 16] : 0;
  tmp[t] = v;
  __syncthreads();
  for (int off = 1; off < 256; off <<= 1) {
    int u = (t >= off) ? tmp[t - off] : 0;
    __syncthreads();
    tmp[t] += u;
    __syncthreads();
  }
  bbase[t] = tmp[t] - v;
  gcursor[t * 16] = tmp[t] - v;
  if (t == 255) rowptr[N] = tmp[255];
  __syncthreads();
  int rv = (t < NB) ? rcnt[t * 16] : 0;
  tmp[t] = rv;
  __syncthreads();
  for (int off = 1; off < 256; off <<= 1) {
    int u = (t >= off) ? tmp[t - off] : 0;
    __syncthreads();
    tmp[t] += u;
    __syncthreads();
  }
  rbase[t] = tmp[t] - rv;
  rcursor[t * 16] = tmp[t] - rv;
}

// P3: merged dual bucket-sort, direct global run writes (no LDS stage).
__global__ __launch_bounds__(256) void kb_scatter2(const void* ei, const int* flag,
                                                   int* gcur, int* rcur,
                                                   unsigned* __restrict__ cpk,
                                                   unsigned* __restrict__ rpk,
                                                   int E, int N) {
  __shared__ int hist[256], lcur[256], gbl[256];
  int t = threadIdx.x;
  int e0 = blockIdx.x * CHUNK;
  int f = *flag;
  int rr[16], cc[16];
#pragma unroll
  for (int k = 0; k < 16; ++k) {
    int e = e0 + k * 256 + t;
    rr[k] = 0; cc[k] = -1;
    if (e < E) {
      int r = edge_at(ei, e, f);
      int c = edge_at(ei, (long long)E + e, f);
      if ((unsigned)r < (unsigned)N && (unsigned)c < (unsigned)N) { rr[k] = r; cc[k] = c; }
    }
  }
  // ---- pass 1: key = c
  hist[t] = 0;
  __syncthreads();
#pragma unroll
  for (int k = 0; k < 16; ++k)
    if (cc[k] >= 0) atomicAdd(&hist[cc[k] >> 8], 1);
  __syncthreads();
  if (hist[t] > 0) gbl[t] = atomicAdd(&gcur[t * 16], hist[t]);
  lcur[t] = 0;
  __syncthreads();
#pragma unroll
  for (int k = 0; k < 16; ++k) {
    if (cc[k] >= 0) {
      int b = cc[k] >> 8;
      int pos = atomicAdd(&lcur[b], 1);
      cpk[gbl[b] + pos] = (unsigned)rr[k] | ((unsigned)(cc[k] & 255) << 24);
    }
  }
  __syncthreads();
  // ---- pass 2: key = r
  hist[t] = 0;
  __syncthreads();
#pragma unroll
  for (int k = 0; k < 16; ++k)
    if (cc[k] >= 0) atomicAdd(&hist[rr[k] >> 8], 1);
  __syncthreads();
  if (hist[t] > 0) gbl[t] = atomicAdd(&rcur[t * 16], hist[t]);
  lcur[t] = 0;
  __syncthreads();
#pragma unroll
  for (int k = 0; k < 16; ++k) {
    if (cc[k] >= 0) {
      int b = rr[k] >> 8;
      int pos = atomicAdd(&lcur[b], 1);
      rpk[gbl[b] + pos] = (unsigned)cc[k] | ((unsigned)(rr[k] & 255) << 24);
    }
  }
}

// P4: per-bucket CSR build + dinv from packed c-sorted records.
__global__ __launch_bounds__(1024) void kb_csr(const unsigned* __restrict__ cpk,
                                               const int* __restrict__ bcnt,
                                               const int* __restrict__ bbase,
                                               int* rowptr, int* src,
                                               float* dinv, int N) {
  __shared__ int hist[256], lcur[256], tmp[256];
  int t = threadIdx.x;
  int b = blockIdx.x;
  int node0 = b << 8;
  int nn = min(256, N - node0);
  int base = bbase[b];
  int cnt = bcnt[b * 16];
  if (t < 256) hist[t] = 0;
  __syncthreads();
  for (int j = t; j < cnt; j += 1024)
    atomicAdd(&hist[cpk[base + j] >> 24], 1);
  __syncthreads();
  if (t < 256) tmp[t] = hist[t];
  __syncthreads();
  for (int off = 1; off < 256; off <<= 1) {
    int u = (t < 256 && t >= off) ? tmp[t - off] : 0;
    __syncthreads();
    if (t < 256) tmp[t] += u;
    __syncthreads();
  }
  if (t < 256) {
    int v = hist[t];
    lcur[t] = tmp[t] - v;
    if (t < nn) {
      rowptr[node0 + t] = base + tmp[t] - v;
      dinv[node0 + t] = rsqrtf((float)(v + 1));  // +1 self-loop
    }
  }
  __syncthreads();
  for (int j = t; j < cnt; j += 1024) {
    unsigned w = cpk[base + j];
    int pos = atomicAdd(&lcur[w >> 24], 1);
    src[base + pos] = (int)(w & 0xFFFFFF);
  }
}

// P5: wp from packed r-sorted records — LDS atomics only
__global__ __launch_bounds__(1024) void kb_wp(const unsigned* __restrict__ rpk,
                                              const int* __restrict__ rcnt,
                                              const int* __restrict__ rbase,
                                              const float* __restrict__ dinv,
                                              float* __restrict__ wp, int N) {
  __shared__ float wpl[256];
  int t = threadIdx.x;
  int b = blockIdx.x;
  int node0 = b << 8;
  int nn = min(256, N - node0);
  int base = rbase[b];
  int cnt = rcnt[b * 16];
  if (t < 256) wpl[t] = 0.f;
  __syncthreads();
  for (int j = t; j < cnt; j += 1024) {
    unsigned w = rpk[base + j];
    atomicAdd(&wpl[w >> 24], dinv[w & 0xFFFFFF]);
  }
  __syncthreads();
  if (t < nn) wp[node0 + t] = wpl[t];
}

// ---------------------------------------------------------------- MFMA GEMM
// Output split into two 64B fp8 planes (ch_new 0..63 / 64..127).
template <int FP8A>
__global__ __launch_bounds__(256) void k_gemm_m(const void* __restrict__ Alo,
                                                const void* __restrict__ Ahi,
                                                const ushort* __restrict__ Wt,
                                                const float* __restrict__ dinv,
                                                uint2* __restrict__ Clo,
                                                uint2* __restrict__ Chi, int N) {
  __shared__ __align__(16) ushort As[64 * 136];
  __shared__ __align__(16) ushort Bs[128 * 136];
  int t = threadIdx.x;
  int row0 = blockIdx.x * 64;

  if (FP8A == 0) {
    const float4* A = (const float4*)Alo;  // [N][32]
    int k4 = t & 31, m0 = t >> 5;
    for (int mm = m0; mm < 64; mm += 8) {
      int gr = row0 + mm;
      float4 v = make_float4(0.f, 0.f, 0.f, 0.f);
      if (gr < N) v = A[(size_t)gr * 32 + k4];
      *(uint2*)&As[mm * 136 + k4 * 4] = make_uint2(bfpack2(v.x, v.y), bfpack2(v.z, v.w));
    }
  } else {
    const uint4* A0 = (const uint4*)Alo;  // [N][4] lo plane
    const uint4* A1 = (const uint4*)Ahi;  // [N][4] hi plane
    int k8 = t & 7, m0 = t >> 3;
    for (int mm = m0; mm < 64; mm += 32) {
      int gr = row0 + mm;
      uint4 v = make_uint4(0, 0, 0, 0);
      if (gr < N) v = (k8 < 4) ? A0[(size_t)gr * 4 + k8] : A1[(size_t)gr * 4 + k8 - 4];
      ushort* d = &As[mm * 136 + k8 * 16];
      *(uint2*)&d[0]  = fp8tobf4(v.x);
      *(uint2*)&d[4]  = fp8tobf4(v.y);
      *(uint2*)&d[8]  = fp8tobf4(v.z);
      *(uint2*)&d[12] = fp8tobf4(v.w);
    }
  }
  {
    const uint4* W4 = (const uint4*)Wt;
    int rw = t >> 1, half = t & 1;
#pragma unroll
    for (int i = 0; i < 8; ++i) {
      uint4 v = W4[rw * 16 + half * 8 + i];
      *(uint4*)&Bs[rw * 136 + half * 64 + i * 8] = v;
    }
  }
  __syncthreads();

  int lane = t & 63, w = t >> 6;
  int m = lane & 15, quad = lane >> 4;
  f32x4 acc[8] = {};
#pragma unroll
  for (int kb = 0; kb < 128; kb += 32) {
    bf16x8 af = *(const bf16x8*)&As[(w * 16 + m) * 136 + kb + quad * 8];
#pragma unroll
    for (int nt = 0; nt < 8; ++nt) {
      bf16x8 bfv = *(const bf16x8*)&Bs[(nt * 16 + m) * 136 + kb + quad * 8];
      acc[nt] = __builtin_amdgcn_mfma_f32_16x16x32_bf16(af, bfv, acc[nt], 0, 0, 0);
    }
  }
  uint2* pl = (m < 8) ? Clo : Chi;
#pragma unroll
  for (int reg = 0; reg < 4; ++reg) {
    int gr = row0 + w * 16 + quad * 4 + reg;
    if (gr < N) {
      float s = dinv[gr];
      unsigned w0 = fp8pk4(acc[0][reg] * s, acc[1][reg] * s, acc[2][reg] * s, acc[3][reg] * s);
      unsigned w1 = fp8pk4(acc[4][reg] * s, acc[5][reg] * s, acc[6][reg] * s, acc[7][reg] * s);
      pl[(size_t)gr * 8 + (m & 7)] = make_uint2(w0, w1);
    }
  }
}

// ---------------------------------------------------------------- aggregate (fp8, one 64B plane)
// 8 lanes/row, uint2 loads: 2x wave count vs R12 for latency hiding.
__global__ __launch_bounds__(256) void k_aggp(const uint2* __restrict__ hh,  // [N][8]
                                              const float* __restrict__ dinv,
                                              const int* __restrict__ rowptr,
                                              const int* __restrict__ src,
                                              const float* __restrict__ biasH,
                                              uint2* __restrict__ outp, int N) {
  int tx = threadIdx.x;  // 0..7 : 8-channel chunk
  int ty = threadIdx.y;  // 0..31: node slot
  float bv[8];
#pragma unroll
  for (int i = 0; i < 8; ++i) bv[i] = biasH[tx * 8 + i];

  for (int c = blockIdx.x * 32 + ty; c < N; c += gridDim.x * 32) {
    float acc[8] = {};
    fp8acc8(hh[(size_t)c * 8 + tx], acc);  // self-loop
    int j = rowptr[c], je = rowptr[c + 1];
    for (; j + 8 <= je; j += 8) {
      int r0 = src[j + 0], r1 = src[j + 1], r2 = src[j + 2], r3 = src[j + 3];
      int r4 = src[j + 4], r5 = src[j + 5], r6 = src[j + 6], r7 = src[j + 7];
      uint2 v0 = hh[(size_t)r0 * 8 + tx];
      uint2 v1 = hh[(size_t)r1 * 8 + tx];
      uint2 v2 = hh[(size_t)r2 * 8 + tx];
      uint2 v3 = hh[(size_t)r3 * 8 + tx];
      uint2 v4 = hh[(size_t)r4 * 8 + tx];
      uint2 v5 = hh[(size_t)r5 * 8 + tx];
      uint2 v6 = hh[(size_t)r6 * 8 + tx];
      uint2 v7 = hh[(size_t)r7 * 8 + tx];
      fp8acc8(v0, acc); fp8acc8(v1, acc); fp8acc8(v2, acc); fp8acc8(v3, acc);
      fp8acc8(v4, acc); fp8acc8(v5, acc); fp8acc8(v6, acc); fp8acc8(v7, acc);
    }
    for (; j < je; ++j) fp8acc8(hh[(size_t)src[j] * 8 + tx], acc);
    float s = dinv[c];
    float o[8];
#pragma unroll
    for (int i = 0; i < 8; ++i) o[i] = fmaxf(acc[i] * s + bv[i], 0.f);
    uint2 ov;
    ov.x = fp8pk4(o[0], o[1], o[2], o[3]);
    ov.y = fp8pk4(o[4], o[5], o[6], o[7]);
    outp[(size_t)c * 8 + tx] = ov;
  }
}

// ---------------------------------------------------------------- fused layer-2 agg + mean-pool
// Same gather as k_aggp but output only the weighted channel sums:
// partial[blk][ch] = sum_c wt(c) * relu(dinv*agg + bias), wt=(dinv+wp)*dinv.
__global__ __launch_bounds__(256) void k_aggu(const uint2* __restrict__ hh,
                                              const float* __restrict__ dinv,
                                              const float* __restrict__ wp,
                                              const int* __restrict__ rowptr,
                                              const int* __restrict__ src,
                                              const float* __restrict__ biasH,
                                              float* __restrict__ partial, int N) {
  __shared__ float red[32][72];
  int tx = threadIdx.x;  // 0..7
  int ty = threadIdx.y;  // 0..31
  float bv[8];
#pragma unroll
  for (int i = 0; i < 8; ++i) bv[i] = biasH[tx * 8 + i];
  float gs[8] = {};

  for (int c = blockIdx.x * 32 + ty; c < N; c += gridDim.x * 32) {
    float acc[8] = {};
    fp8acc8(hh[(size_t)c * 8 + tx], acc);  // self-loop
    int j = rowptr[c], je = rowptr[c + 1];
    for (; j + 8 <= je; j += 8) {
      int r0 = src[j + 0], r1 = src[j + 1], r2 = src[j + 2], r3 = src[j + 3];
      int r4 = src[j + 4], r5 = src[j + 5], r6 = src[j + 6], r7 = src[j + 7];
      uint2 v0 = hh[(size_t)r0 * 8 + tx];
      uint2 v1 = hh[(size_t)r1 * 8 + tx];
      uint2 v2 = hh[(size_t)r2 * 8 + tx];
      uint2 v3 = hh[(size_t)r3 * 8 + tx];
      uint2 v4 = hh[(size_t)r4 * 8 + tx];
      uint2 v5 = hh[(size_t)r5 * 8 + tx];
      uint2 v6 = hh[(size_t)r6 * 8 + tx];
      uint2 v7 = hh[(size_t)r7 * 8 + tx];
      fp8acc8(v0, acc); fp8acc8(v1, acc); fp8acc8(v2, acc); fp8acc8(v3, acc);
      fp8acc8(v4, acc); fp8acc8(v5, acc); fp8acc8(v6, acc); fp8acc8(v7, acc);
    }
    for (; j < je; ++j) fp8acc8(hh[(size_t)src[j] * 8 + tx], acc);
    float d = dinv[c];
    float wt = (d + wp[c]) * d;
#pragma unroll
    for (int i = 0; i < 8; ++i)
      gs[i] += wt * fmaxf(acc[i] * d + bv[i], 0.f);
  }
#pragma unroll
  for (int i = 0; i < 8; ++i) red[ty][tx * 8 + i] = gs[i];
  __syncthreads();
  for (int s = 16; s > 0; s >>= 1) {
    if (ty < s) {
#pragma unroll
      for (int i = 0; i < 8; ++i) red[ty][tx * 8 + i] += red[ty + s][tx * 8 + i];
    }
    __syncthreads();
  }
  if (ty == 0) {
#pragma unroll
    for (int i = 0; i < 8; ++i)
      partial[(size_t)blockIdx.x * 64 + tx * 8 + i] = red[0][tx * 8 + i];
  }
}

// ---------------------------------------------------------------- epilogue (1024 thr)
// p_lo/p_hi: per-block partials for permuted channels 0..63 / 64..127.
__global__ __launch_bounds__(1024) void k_final(const float* __restrict__ p_lo,
                                                const float* __restrict__ p_hi,
                                                int nb,
                                                const float* __restrict__ W3,
                                                const float* __restrict__ b3,
                                                const float* __restrict__ Wl,
                                                const float* __restrict__ bl,
                                                float* __restrict__ out, float invN) {
  __shared__ float us[CH];
  __shared__ float red[8][CH];
  int t = threadIdx.x;
  int ch = t & 127, g = t >> 7;
  const float* P = (ch < 64) ? (p_lo + ch) : (p_hi + (ch - 64));
  float s = 0.f;
  for (int b = g; b < nb; b += 8) s += P[(size_t)b * 64];
  red[g][ch] = s;
  __syncthreads();
  if (g == 0) {
    float u = s;
#pragma unroll
    for (int k = 1; k < 8; ++k) u += red[k][ch];
    us[ch] = u * invN;
  }
  __syncthreads();
  float p = 0.f;
#pragma unroll
  for (int k = 0; k < 16; ++k) {
    int kk = g * 16 + k;
    int ko = (kk & 7) * 16 + (kk >> 3);  // un-permute channel
    p += us[kk] * W3[(size_t)ko * CH + ch];
  }
  red[g][ch] = p;
  __syncthreads();
  if (g == 0) {
    float S = red[0][ch];
#pragma unroll
    for (int k = 1; k < 8; ++k) S += red[k][ch];
    us[ch] = (S + b3[ch]) * Wl[ch];
  }
  __syncthreads();
  for (int off = 64; off > 0; off >>= 1) {
    if (t < off) us[t] += us[t + off];
    __syncthreads();
  }
  if (t == 0) out[0] = 1.f / (1.f + expf(-(us[0] + bl[0])));
}

// ---------------------------------------------------------------- launch

extern "C" void kernel_launch(void* const* d_in, const int* in_sizes, int n_in,
                              void* d_out, int out_size, void* d_ws, size_t ws_size,
                              hipStream_t stream) {
  const float* x  = (const float*)d_in[0];
  const void*  ei = d_in[1];
  const float* W1 = (const float*)d_in[3];
  const float* b1 = (const float*)d_in[4];
  const float* W2 = (const float*)d_in[5];
  const float* b2 = (const float*)d_in[6];
  const float* W3 = (const float*)d_in[7];
  const float* b3 = (const float*)d_in[8];
  const float* Wl = (const float*)d_in[9];
  const float* bl = (const float*)d_in[10];
  float* out = (float*)d_out;

  const int N = in_sizes[0] / CH;
  const int E = in_sizes[1] / 2;
  const int NB = (N + 255) >> 8;
  const int nbA = (N + 31) / 32;  // agg grid

  char* ws = (char*)d_ws;
  size_t off = 0;
  auto alloc = [&](size_t bytes) -> void* {
    void* p = ws + off;
    off += (bytes + 511) & ~(size_t)511;
    return p;
  };
  int*      flag   = (int*)alloc(4);
  float*    dinv   = (float*)alloc((size_t)N * 4);
  float*    wp     = (float*)alloc((size_t)N * 4);
  int*      rowptr = (int*)alloc((size_t)(N + 1) * 4);
  int*      bcnt   = (int*)alloc(256 * 16 * 4);
  int*      bbase  = (int*)alloc(256 * 4);
  int*      gcur   = (int*)alloc(256 * 16 * 4);
  int*      rcnt   = (int*)alloc(256 * 16 * 4);
  int*      rbase  = (int*)alloc(256 * 4);
  int*      rcur   = (int*)alloc(256 * 16 * 4);
  float*    p_lo   = (float*)alloc((size_t)nbA * 64 * 4);
  float*    p_hi   = (float*)alloc((size_t)nbA * 64 * 4);
  ushort*   Wt1    = (ushort*)alloc(128 * 128 * 2);
  ushort*   Wt2    = (ushort*)alloc(128 * 128 * 2);
  float*    b1p    = (float*)alloc(CH * 4);
  float*    b2p    = (float*)alloc(CH * 4);
  int*      src    = (int*)alloc((size_t)E * 4);
  unsigned* cpk    = (unsigned*)alloc((size_t)E * 4);
  unsigned* rpk    = (unsigned*)alloc((size_t)E * 4);
  uint2*    hlo    = (uint2*)alloc((size_t)N * 64);  // fp8 plane ch 0..63
  uint2*    hhi    = (uint2*)alloc((size_t)N * 64);
  uint2*    xlo    = (uint2*)alloc((size_t)N * 64);
  uint2*    xhi    = (uint2*)alloc((size_t)N * 64);

  const int nCk = (E + CHUNK - 1) / CHUNK;

  // ---- preprocessing
  k_setup<<<1, 256, 0, stream>>>((const int*)ei, flag, bcnt, rcnt,
                                 W1, b1, W2, b2, Wt1, Wt2, b1p, b2p);
  kb_count<<<nCk, 256, 0, stream>>>(ei, flag, bcnt, rcnt, E, N);
  kb_scan<<<1, 256, 0, stream>>>(bcnt, bbase, gcur, rcnt, rbase, rcur, rowptr, NB, N);
  kb_scatter2<<<nCk, 256, 0, stream>>>(ei, flag, gcur, rcur, cpk, rpk, E, N);
  kb_csr<<<NB, 1024, 0, stream>>>(cpk, bcnt, bbase, rowptr, src, dinv, N);
  kb_wp<<<NB, 1024, 0, stream>>>(rpk, rcnt, rbase, dinv, wp, N);

  // ---- layers 1 & 2 (MFMA GEMMs + split-plane gather-aggregates)
  const int gblocks = (N + 63) / 64;
  dim3 ablk(8, 32);

  k_gemm_m<0><<<gblocks, 256, 0, stream>>>(x, nullptr, Wt1, dinv, (uint2*)hlo, (uint2*)hhi, N);
  k_aggp<<<nbA, ablk, 0, stream>>>(hlo, dinv, rowptr, src, b1p,      xlo, N);
  k_aggp<<<nbA, ablk, 0, stream>>>(hhi, dinv, rowptr, src, b1p + 64, xhi, N);
  k_gemm_m<1><<<gblocks, 256, 0, stream>>>(xlo, xhi, Wt2, dinv, (uint2*)hlo, (uint2*)hhi, N);
  // layer-2 aggs fused with mean-pool: no feature writes, per-block partials
  k_aggu<<<nbA, ablk, 0, stream>>>(hlo, dinv, wp, rowptr, src, b2p,      p_lo, N);
  k_aggu<<<nbA, ablk, 0, stream>>>(hhi, dinv, wp, rowptr, src, b2p + 64, p_hi, N);

  k_final<<<1, 1024, 0, stream>>>(p_lo, p_hi, nbA, W3, b3, Wl, bl, out, 1.0f / (float)N);
}

// Round 15
// 317.200 us; speedup vs baseline: 1.1319x; 1.1319x over previous
//
#include <hip/hip_runtime.h>

#define CH 128
#define CHUNK 4096

typedef float v2f __attribute__((ext_vector_type(2)));
typedef __attribute__((ext_vector_type(8))) short bf16x8;   // 8 bf16 (4 VGPRs)
typedef __attribute__((ext_vector_type(4))) float f32x4;    // MFMA acc

// ---------------------------------------------------------------- fp8 helpers (OCP e4m3)

__device__ __forceinline__ void fp8acc4(unsigned w, float* a) {
  v2f p0 = __builtin_amdgcn_cvt_pk_f32_fp8(w, false);
  v2f p1 = __builtin_amdgcn_cvt_pk_f32_fp8(w, true);
  a[0] += p0.x; a[1] += p0.y; a[2] += p1.x; a[3] += p1.y;
}
__device__ __forceinline__ void fp8acc8(uint2 v, float* a) {
  fp8acc4(v.x, a); fp8acc4(v.y, a + 4);
}
__device__ __forceinline__ unsigned fp8pk4(float a, float b, float c, float d) {
  int w = 0;
  w = __builtin_amdgcn_cvt_pk_fp8_f32(a, b, w, false);
  w = __builtin_amdgcn_cvt_pk_fp8_f32(c, d, w, true);
  return (unsigned)w;
}

// ---------------------------------------------------------------- bf16 helpers

__device__ __forceinline__ unsigned bfpack2(float a, float b) {
  unsigned ua = __float_as_uint(a); ua += 0x7FFF + ((ua >> 16) & 1);
  unsigned ub = __float_as_uint(b); ub += 0x7FFF + ((ub >> 16) & 1);
  return (ua >> 16) | (ub & 0xFFFF0000u);
}
__device__ __forceinline__ ushort bf16of(float a) {
  unsigned ua = __float_as_uint(a); ua += 0x7FFF + ((ua >> 16) & 1);
  return (ushort)(ua >> 16);
}
__device__ __forceinline__ uint2 fp8tobf4(unsigned w) {  // 4 fp8 -> 4 bf16
  v2f p0 = __builtin_amdgcn_cvt_pk_f32_fp8(w, false);
  v2f p1 = __builtin_amdgcn_cvt_pk_f32_fp8(w, true);
  return make_uint2(bfpack2(p0.x, p0.y), bfpack2(p1.x, p1.y));
}

// ---------------------------------------------------------------- utilities

__device__ __forceinline__ int edge_at(const void* ei, long long i, int is64) {
  if (is64) return (int)((const long long*)ei)[i];
  return ((const int*)ei)[i];
}

// merged setup: dtype detect + counter zero + bf16 weight prep (1 block)
__global__ void k_setup(const int* ei, int* flag, int* bcnt, int* rcnt,
                        const float* __restrict__ W1, const float* __restrict__ b1,
                        const float* __restrict__ W2, const float* __restrict__ b2,
                        ushort* __restrict__ Wt1, ushort* __restrict__ Wt2,
                        float* __restrict__ b1p, float* __restrict__ b2p) {
  int t = threadIdx.x;
  if (t == 0) {
    int is64 = 1;
    for (int k = 1; k < 128; k += 2)
      if (ei[k] != 0) { is64 = 0; break; }
    *flag = is64;
  }
  for (int i = t; i < 256 * 16; i += 256) { bcnt[i] = 0; rcnt[i] = 0; }
  for (int i = t; i < 128 * 128; i += 256) {
    int n = i >> 7, k = i & 127;
    Wt1[i] = bf16of(W1[(size_t)k * CH + n]);
    int ko = (k & 7) * 16 + (k >> 3);
    Wt2[i] = bf16of(W2[(size_t)ko * CH + n]);
  }
  if (t < CH) {
    int o = (t & 7) * 16 + (t >> 3);
    b1p[t] = b1[o];
    b2p[t] = b2[o];
  }
}

// P1: per-bucket edge counts for BOTH c-buckets and r-buckets
__global__ __launch_bounds__(256) void kb_count(const void* ei, const int* flag,
                                                int* bcnt, int* rcnt, int E, int N) {
  __shared__ int hist[256], rhist[256];
  int t = threadIdx.x;
  hist[t] = 0; rhist[t] = 0;
  __syncthreads();
  int f = *flag;
  for (int e = blockIdx.x * 256 + t; e < E; e += gridDim.x * 256) {
    int r = edge_at(ei, e, f);
    int c = edge_at(ei, (long long)E + e, f);
    if ((unsigned)r < (unsigned)N && (unsigned)c < (unsigned)N) {
      atomicAdd(&hist[c >> 8], 1);
      atomicAdd(&rhist[r >> 8], 1);
    }
  }
  __syncthreads();
  if (hist[t] > 0) atomicAdd(&bcnt[t * 16], hist[t]);
  if (rhist[t] > 0) atomicAdd(&rcnt[t * 16], rhist[t]);
}

// P2: scan both bucket-count arrays -> bases + cursors; rowptr[N]=total
__global__ void kb_scan(const int* bcnt, int* bbase, int* gcursor,
                        const int* rcnt, int* rbase, int* rcursor,
                        int* rowptr, int NB, int N) {
  __shared__ int tmp[256];
  int t = threadIdx.x;
  int v = (t < NB) ? bcnt[t * 16] : 0;
  tmp[t] = v;
  __syncthreads();
  for (int off = 1; off < 256; off <<= 1) {
    int u = (t >= off) ? tmp[t - off] : 0;
    __syncthreads();
    tmp[t] += u;
    __syncthreads();
  }
  bbase[t] = tmp[t] - v;
  gcursor[t * 16] = tmp[t] - v;
  if (t == 255) rowptr[N] = tmp[255];
  __syncthreads();
  int rv = (t < NB) ? rcnt[t * 16] : 0;
  tmp[t] = rv;
  __syncthreads();
  for (int off = 1; off < 256; off <<= 1) {
    int u = (t >= off) ? tmp[t - off] : 0;
    __syncthreads();
    tmp[t] += u;
    __syncthreads();
  }
  rbase[t] = tmp[t] - rv;
  rcursor[t * 16] = tmp[t] - rv;
}

// P3: merged dual bucket-sort, direct global run writes (no LDS stage).
__global__ __launch_bounds__(256) void kb_scatter2(const void* ei, const int* flag,
                                                   int* gcur, int* rcur,
                                                   unsigned* __restrict__ cpk,
                                                   unsigned* __restrict__ rpk,
                                                   int E, int N) {
  __shared__ int hist[256], lcur[256], gbl[256];
  int t = threadIdx.x;
  int e0 = blockIdx.x * CHUNK;
  int f = *flag;
  int rr[16], cc[16];
#pragma unroll
  for (int k = 0; k < 16; ++k) {
    int e = e0 + k * 256 + t;
    rr[k] = 0; cc[k] = -1;
    if (e < E) {
      int r = edge_at(ei, e, f);
      int c = edge_at(ei, (long long)E + e, f);
      if ((unsigned)r < (unsigned)N && (unsigned)c < (unsigned)N) { rr[k] = r; cc[k] = c; }
    }
  }
  // ---- pass 1: key = c
  hist[t] = 0;
  __syncthreads();
#pragma unroll
  for (int k = 0; k < 16; ++k)
    if (cc[k] >= 0) atomicAdd(&hist[cc[k] >> 8], 1);
  __syncthreads();
  if (hist[t] > 0) gbl[t] = atomicAdd(&gcur[t * 16], hist[t]);
  lcur[t] = 0;
  __syncthreads();
#pragma unroll
  for (int k = 0; k < 16; ++k) {
    if (cc[k] >= 0) {
      int b = cc[k] >> 8;
      int pos = atomicAdd(&lcur[b], 1);
      cpk[gbl[b] + pos] = (unsigned)rr[k] | ((unsigned)(cc[k] & 255) << 24);
    }
  }
  __syncthreads();
  // ---- pass 2: key = r
  hist[t] = 0;
  __syncthreads();
#pragma unroll
  for (int k = 0; k < 16; ++k)
    if (cc[k] >= 0) atomicAdd(&hist[rr[k] >> 8], 1);
  __syncthreads();
  if (hist[t] > 0) gbl[t] = atomicAdd(&rcur[t * 16], hist[t]);
  lcur[t] = 0;
  __syncthreads();
#pragma unroll
  for (int k = 0; k < 16; ++k) {
    if (cc[k] >= 0) {
      int b = rr[k] >> 8;
      int pos = atomicAdd(&lcur[b], 1);
      rpk[gbl[b] + pos] = (unsigned)cc[k] | ((unsigned)(rr[k] & 255) << 24);
    }
  }
}

// P4: per-bucket CSR build + dinv from packed c-sorted records.
__global__ __launch_bounds__(1024) void kb_csr(const unsigned* __restrict__ cpk,
                                               const int* __restrict__ bcnt,
                                               const int* __restrict__ bbase,
                                               int* rowptr, int* src,
                                               float* dinv, int N) {
  __shared__ int hist[256], lcur[256], tmp[256];
  int t = threadIdx.x;
  int b = blockIdx.x;
  int node0 = b << 8;
  int nn = min(256, N - node0);
  int base = bbase[b];
  int cnt = bcnt[b * 16];
  if (t < 256) hist[t] = 0;
  __syncthreads();
  for (int j = t; j < cnt; j += 1024)
    atomicAdd(&hist[cpk[base + j] >> 24], 1);
  __syncthreads();
  if (t < 256) tmp[t] = hist[t];
  __syncthreads();
  for (int off = 1; off < 256; off <<= 1) {
    int u = (t < 256 && t >= off) ? tmp[t - off] : 0;
    __syncthreads();
    if (t < 256) tmp[t] += u;
    __syncthreads();
  }
  if (t < 256) {
    int v = hist[t];
    lcur[t] = tmp[t] - v;
    if (t < nn) {
      rowptr[node0 + t] = base + tmp[t] - v;
      dinv[node0 + t] = rsqrtf((float)(v + 1));  // +1 self-loop
    }
  }
  __syncthreads();
  for (int j = t; j < cnt; j += 1024) {
    unsigned w = cpk[base + j];
    int pos = atomicAdd(&lcur[w >> 24], 1);
    src[base + pos] = (int)(w & 0xFFFFFF);
  }
}

// P5: wp from packed r-sorted records — LDS atomics only
__global__ __launch_bounds__(1024) void kb_wp(const unsigned* __restrict__ rpk,
                                              const int* __restrict__ rcnt,
                                              const int* __restrict__ rbase,
                                              const float* __restrict__ dinv,
                                              float* __restrict__ wp, int N) {
  __shared__ float wpl[256];
  int t = threadIdx.x;
  int b = blockIdx.x;
  int node0 = b << 8;
  int nn = min(256, N - node0);
  int base = rbase[b];
  int cnt = rcnt[b * 16];
  if (t < 256) wpl[t] = 0.f;
  __syncthreads();
  for (int j = t; j < cnt; j += 1024) {
    unsigned w = rpk[base + j];
    atomicAdd(&wpl[w >> 24], dinv[w & 0xFFFFFF]);
  }
  __syncthreads();
  if (t < nn) wp[node0 + t] = wpl[t];
}

// ---------------------------------------------------------------- MFMA GEMM
// Output split into two 64B fp8 planes (ch_new 0..63 / 64..127).
template <int FP8A>
__global__ __launch_bounds__(256) void k_gemm_m(const void* __restrict__ Alo,
                                                const void* __restrict__ Ahi,
                                                const ushort* __restrict__ Wt,
                                                const float* __restrict__ dinv,
                                                uint2* __restrict__ Clo,
                                                uint2* __restrict__ Chi, int N) {
  __shared__ __align__(16) ushort As[64 * 136];
  __shared__ __align__(16) ushort Bs[128 * 136];
  int t = threadIdx.x;
  int row0 = blockIdx.x * 64;

  if (FP8A == 0) {
    const float4* A = (const float4*)Alo;  // [N][32]
    int k4 = t & 31, m0 = t >> 5;
    for (int mm = m0; mm < 64; mm += 8) {
      int gr = row0 + mm;
      float4 v = make_float4(0.f, 0.f, 0.f, 0.f);
      if (gr < N) v = A[(size_t)gr * 32 + k4];
      *(uint2*)&As[mm * 136 + k4 * 4] = make_uint2(bfpack2(v.x, v.y), bfpack2(v.z, v.w));
    }
  } else {
    const uint4* A0 = (const uint4*)Alo;  // [N][4] lo plane
    const uint4* A1 = (const uint4*)Ahi;  // [N][4] hi plane
    int k8 = t & 7, m0 = t >> 3;
    for (int mm = m0; mm < 64; mm += 32) {
      int gr = row0 + mm;
      uint4 v = make_uint4(0, 0, 0, 0);
      if (gr < N) v = (k8 < 4) ? A0[(size_t)gr * 4 + k8] : A1[(size_t)gr * 4 + k8 - 4];
      ushort* d = &As[mm * 136 + k8 * 16];
      *(uint2*)&d[0]  = fp8tobf4(v.x);
      *(uint2*)&d[4]  = fp8tobf4(v.y);
      *(uint2*)&d[8]  = fp8tobf4(v.z);
      *(uint2*)&d[12] = fp8tobf4(v.w);
    }
  }
  {
    const uint4* W4 = (const uint4*)Wt;
    int rw = t >> 1, half = t & 1;
#pragma unroll
    for (int i = 0; i < 8; ++i) {
      uint4 v = W4[rw * 16 + half * 8 + i];
      *(uint4*)&Bs[rw * 136 + half * 64 + i * 8] = v;
    }
  }
  __syncthreads();

  int lane = t & 63, w = t >> 6;
  int m = lane & 15, quad = lane >> 4;
  f32x4 acc[8] = {};
#pragma unroll
  for (int kb = 0; kb < 128; kb += 32) {
    bf16x8 af = *(const bf16x8*)&As[(w * 16 + m) * 136 + kb + quad * 8];
#pragma unroll
    for (int nt = 0; nt < 8; ++nt) {
      bf16x8 bfv = *(const bf16x8*)&Bs[(nt * 16 + m) * 136 + kb + quad * 8];
      acc[nt] = __builtin_amdgcn_mfma_f32_16x16x32_bf16(af, bfv, acc[nt], 0, 0, 0);
    }
  }
  uint2* pl = (m < 8) ? Clo : Chi;
#pragma unroll
  for (int reg = 0; reg < 4; ++reg) {
    int gr = row0 + w * 16 + quad * 4 + reg;
    if (gr < N) {
      float s = dinv[gr];
      unsigned w0 = fp8pk4(acc[0][reg] * s, acc[1][reg] * s, acc[2][reg] * s, acc[3][reg] * s);
      unsigned w1 = fp8pk4(acc[4][reg] * s, acc[5][reg] * s, acc[6][reg] * s, acc[7][reg] * s);
      pl[(size_t)gr * 8 + (m & 7)] = make_uint2(w0, w1);
    }
  }
}

// ---------------------------------------------------------------- aggregate (fp8, one 64B plane)
// 8 lanes/row, uint2 loads. launch_bounds(256,6): cap VGPR<=85 -> 24 waves/CU.
__global__ __launch_bounds__(256, 6) void k_aggp(const uint2* __restrict__ hh,  // [N][8]
                                                 const float* __restrict__ dinv,
                                                 const int* __restrict__ rowptr,
                                                 const int* __restrict__ src,
                                                 const float* __restrict__ biasH,
                                                 uint2* __restrict__ outp, int N) {
  int tx = threadIdx.x;  // 0..7 : 8-channel chunk
  int ty = threadIdx.y;  // 0..31: node slot
  float bv[8];
#pragma unroll
  for (int i = 0; i < 8; ++i) bv[i] = biasH[tx * 8 + i];

  for (int c = blockIdx.x * 32 + ty; c < N; c += gridDim.x * 32) {
    float acc[8] = {};
    fp8acc8(hh[(size_t)c * 8 + tx], acc);  // self-loop
    int j = rowptr[c], je = rowptr[c + 1];
    for (; j + 8 <= je; j += 8) {
      int r0 = src[j + 0], r1 = src[j + 1], r2 = src[j + 2], r3 = src[j + 3];
      int r4 = src[j + 4], r5 = src[j + 5], r6 = src[j + 6], r7 = src[j + 7];
      uint2 v0 = hh[(size_t)r0 * 8 + tx];
      uint2 v1 = hh[(size_t)r1 * 8 + tx];
      uint2 v2 = hh[(size_t)r2 * 8 + tx];
      uint2 v3 = hh[(size_t)r3 * 8 + tx];
      uint2 v4 = hh[(size_t)r4 * 8 + tx];
      uint2 v5 = hh[(size_t)r5 * 8 + tx];
      uint2 v6 = hh[(size_t)r6 * 8 + tx];
      uint2 v7 = hh[(size_t)r7 * 8 + tx];
      fp8acc8(v0, acc); fp8acc8(v1, acc); fp8acc8(v2, acc); fp8acc8(v3, acc);
      fp8acc8(v4, acc); fp8acc8(v5, acc); fp8acc8(v6, acc); fp8acc8(v7, acc);
    }
    for (; j < je; ++j) fp8acc8(hh[(size_t)src[j] * 8 + tx], acc);
    float s = dinv[c];
    float o[8];
#pragma unroll
    for (int i = 0; i < 8; ++i) o[i] = fmaxf(acc[i] * s + bv[i], 0.f);
    uint2 ov;
    ov.x = fp8pk4(o[0], o[1], o[2], o[3]);
    ov.y = fp8pk4(o[4], o[5], o[6], o[7]);
    outp[(size_t)c * 8 + tx] = ov;
  }
}

// ---------------------------------------------------------------- fused layer-2 agg + mean-pool
__global__ __launch_bounds__(256, 6) void k_aggu(const uint2* __restrict__ hh,
                                                 const float* __restrict__ dinv,
                                                 const float* __restrict__ wp,
                                                 const int* __restrict__ rowptr,
                                                 const int* __restrict__ src,
                                                 const float* __restrict__ biasH,
                                                 float* __restrict__ partial, int N) {
  __shared__ float red[32][72];
  int tx = threadIdx.x;  // 0..7
  int ty = threadIdx.y;  // 0..31
  float bv[8];
#pragma unroll
  for (int i = 0; i < 8; ++i) bv[i] = biasH[tx * 8 + i];
  float gs[8] = {};

  for (int c = blockIdx.x * 32 + ty; c < N; c += gridDim.x * 32) {
    float acc[8] = {};
    fp8acc8(hh[(size_t)c * 8 + tx], acc);  // self-loop
    int j = rowptr[c], je = rowptr[c + 1];
    for (; j + 8 <= je; j += 8) {
      int r0 = src[j + 0], r1 = src[j + 1], r2 = src[j + 2], r3 = src[j + 3];
      int r4 = src[j + 4], r5 = src[j + 5], r6 = src[j + 6], r7 = src[j + 7];
      uint2 v0 = hh[(size_t)r0 * 8 + tx];
      uint2 v1 = hh[(size_t)r1 * 8 + tx];
      uint2 v2 = hh[(size_t)r2 * 8 + tx];
      uint2 v3 = hh[(size_t)r3 * 8 + tx];
      uint2 v4 = hh[(size_t)r4 * 8 + tx];
      uint2 v5 = hh[(size_t)r5 * 8 + tx];
      uint2 v6 = hh[(size_t)r6 * 8 + tx];
      uint2 v7 = hh[(size_t)r7 * 8 + tx];
      fp8acc8(v0, acc); fp8acc8(v1, acc); fp8acc8(v2, acc); fp8acc8(v3, acc);
      fp8acc8(v4, acc); fp8acc8(v5, acc); fp8acc8(v6, acc); fp8acc8(v7, acc);
    }
    for (; j < je; ++j) fp8acc8(hh[(size_t)src[j] * 8 + tx], acc);
    float d = dinv[c];
    float wt = (d + wp[c]) * d;
#pragma unroll
    for (int i = 0; i < 8; ++i)
      gs[i] += wt * fmaxf(acc[i] * d + bv[i], 0.f);
  }
#pragma unroll
  for (int i = 0; i < 8; ++i) red[ty][tx * 8 + i] = gs[i];
  __syncthreads();
  for (int s = 16; s > 0; s >>= 1) {
    if (ty < s) {
#pragma unroll
      for (int i = 0; i < 8; ++i) red[ty][tx * 8 + i] += red[ty + s][tx * 8 + i];
    }
    __syncthreads();
  }
  if (ty == 0) {
#pragma unroll
    for (int i = 0; i < 8; ++i)
      partial[(size_t)blockIdx.x * 64 + tx * 8 + i] = red[0][tx * 8 + i];
  }
}

// ---------------------------------------------------------------- epilogue (1024 thr)
// R14 lesson: stage-1 must be multi-accumulator unrolled (8 outstanding loads).
__global__ __launch_bounds__(1024) void k_final(const float* __restrict__ p_lo,
                                                const float* __restrict__ p_hi,
                                                int nb,
                                                const float* __restrict__ W3,
                                                const float* __restrict__ b3,
                                                const float* __restrict__ Wl,
                                                const float* __restrict__ bl,
                                                float* __restrict__ out, float invN) {
  __shared__ float us[CH];
  __shared__ float red[8][CH];
  int t = threadIdx.x;
  int ch = t & 127, g = t >> 7;
  const float* P = (ch < 64) ? (p_lo + ch) : (p_hi + (ch - 64));
  float s0 = 0.f, s1 = 0.f, s2 = 0.f, s3 = 0.f;
  float s4 = 0.f, s5 = 0.f, s6 = 0.f, s7 = 0.f;
  int b = g;
  for (; b + 64 <= nb; b += 64) {
    s0 += P[(size_t)(b +  0) * 64];
    s1 += P[(size_t)(b +  8) * 64];
    s2 += P[(size_t)(b + 16) * 64];
    s3 += P[(size_t)(b + 24) * 64];
    s4 += P[(size_t)(b + 32) * 64];
    s5 += P[(size_t)(b + 40) * 64];
    s6 += P[(size_t)(b + 48) * 64];
    s7 += P[(size_t)(b + 56) * 64];
  }
  for (; b < nb; b += 8) s0 += P[(size_t)b * 64];
  float s = ((s0 + s1) + (s2 + s3)) + ((s4 + s5) + (s6 + s7));
  red[g][ch] = s;
  __syncthreads();
  if (g == 0) {
    float u = s;
#pragma unroll
    for (int k = 1; k < 8; ++k) u += red[k][ch];
    us[ch] = u * invN;
  }
  __syncthreads();
  float p = 0.f;
#pragma unroll
  for (int k = 0; k < 16; ++k) {
    int kk = g * 16 + k;
    int ko = (kk & 7) * 16 + (kk >> 3);  // un-permute channel
    p += us[kk] * W3[(size_t)ko * CH + ch];
  }
  red[g][ch] = p;
  __syncthreads();
  if (g == 0) {
    float S = red[0][ch];
#pragma unroll
    for (int k = 1; k < 8; ++k) S += red[k][ch];
    us[ch] = (S + b3[ch]) * Wl[ch];
  }
  __syncthreads();
  for (int off = 64; off > 0; off >>= 1) {
    if (t < off) us[t] += us[t + off];
    __syncthreads();
  }
  if (t == 0) out[0] = 1.f / (1.f + expf(-(us[0] + bl[0])));
}

// ---------------------------------------------------------------- launch

extern "C" void kernel_launch(void* const* d_in, const int* in_sizes, int n_in,
                              void* d_out, int out_size, void* d_ws, size_t ws_size,
                              hipStream_t stream) {
  const float* x  = (const float*)d_in[0];
  const void*  ei = d_in[1];
  const float* W1 = (const float*)d_in[3];
  const float* b1 = (const float*)d_in[4];
  const float* W2 = (const float*)d_in[5];
  const float* b2 = (const float*)d_in[6];
  const float* W3 = (const float*)d_in[7];
  const float* b3 = (const float*)d_in[8];
  const float* Wl = (const float*)d_in[9];
  const float* bl = (const float*)d_in[10];
  float* out = (float*)d_out;

  const int N = in_sizes[0] / CH;
  const int E = in_sizes[1] / 2;
  const int NB = (N + 255) >> 8;
  const int nbA = (N + 31) / 32;  // agg grid

  char* ws = (char*)d_ws;
  size_t off = 0;
  auto alloc = [&](size_t bytes) -> void* {
    void* p = ws + off;
    off += (bytes + 511) & ~(size_t)511;
    return p;
  };
  int*      flag   = (int*)alloc(4);
  float*    dinv   = (float*)alloc((size_t)N * 4);
  float*    wp     = (float*)alloc((size_t)N * 4);
  int*      rowptr = (int*)alloc((size_t)(N + 1) * 4);
  int*      bcnt   = (int*)alloc(256 * 16 * 4);
  int*      bbase  = (int*)alloc(256 * 4);
  int*      gcur   = (int*)alloc(256 * 16 * 4);
  int*      rcnt   = (int*)alloc(256 * 16 * 4);
  int*      rbase  = (int*)alloc(256 * 4);
  int*      rcur   = (int*)alloc(256 * 16 * 4);
  float*    p_lo   = (float*)alloc((size_t)nbA * 64 * 4);
  float*    p_hi   = (float*)alloc((size_t)nbA * 64 * 4);
  ushort*   Wt1    = (ushort*)alloc(128 * 128 * 2);
  ushort*   Wt2    = (ushort*)alloc(128 * 128 * 2);
  float*    b1p    = (float*)alloc(CH * 4);
  float*    b2p    = (float*)alloc(CH * 4);
  int*      src    = (int*)alloc((size_t)E * 4);
  unsigned* cpk    = (unsigned*)alloc((size_t)E * 4);
  unsigned* rpk    = (unsigned*)alloc((size_t)E * 4);
  uint2*    hlo    = (uint2*)alloc((size_t)N * 64);  // fp8 plane ch 0..63
  uint2*    hhi    = (uint2*)alloc((size_t)N * 64);
  uint2*    xlo    = (uint2*)alloc((size_t)N * 64);
  uint2*    xhi    = (uint2*)alloc((size_t)N * 64);

  const int nCk = (E + CHUNK - 1) / CHUNK;

  // ---- preprocessing
  k_setup<<<1, 256, 0, stream>>>((const int*)ei, flag, bcnt, rcnt,
                                 W1, b1, W2, b2, Wt1, Wt2, b1p, b2p);
  kb_count<<<nCk, 256, 0, stream>>>(ei, flag, bcnt, rcnt, E, N);
  kb_scan<<<1, 256, 0, stream>>>(bcnt, bbase, gcur, rcnt, rbase, rcur, rowptr, NB, N);
  kb_scatter2<<<nCk, 256, 0, stream>>>(ei, flag, gcur, rcur, cpk, rpk, E, N);
  kb_csr<<<NB, 1024, 0, stream>>>(cpk, bcnt, bbase, rowptr, src, dinv, N);
  kb_wp<<<NB, 1024, 0, stream>>>(rpk, rcnt, rbase, dinv, wp, N);

  // ---- layers 1 & 2 (MFMA GEMMs + split-plane gather-aggregates)
  const int gblocks = (N + 63) / 64;
  dim3 ablk(8, 32);

  k_gemm_m<0><<<gblocks, 256, 0, stream>>>(x, nullptr, Wt1, dinv, (uint2*)hlo, (uint2*)hhi, N);
  k_aggp<<<nbA, ablk, 0, stream>>>(hlo, dinv, rowptr, src, b1p,      xlo, N);
  k_aggp<<<nbA, ablk, 0, stream>>>(hhi, dinv, rowptr, src, b1p + 64, xhi, N);
  k_gemm_m<1><<<gblocks, 256, 0, stream>>>(xlo, xhi, Wt2, dinv, (uint2*)hlo, (uint2*)hhi, N);
  // layer-2 aggs fused with mean-pool: no feature writes, per-block partials
  k_aggu<<<nbA, ablk, 0, stream>>>(hlo, dinv, wp, rowptr, src, b2p,      p_lo, N);
  k_aggu<<<nbA, ablk, 0, stream>>>(hhi, dinv, wp, rowptr, src, b2p + 64, p_hi, N);

  k_final<<<1, 1024, 0, stream>>>(p_lo, p_hi, nbA, W3, b3, Wl, bl, out, 1.0f / (float)N);
}